// Round 12
// baseline (91.844 us; speedup 1.0000x reference)
//
#include <hip/hip_runtime.h>
#include <stdint.h>

#define NIN 256
#define RPB 32              // rows per block: two 16-row MFMA tiles, row-paired

typedef float    f32x4 __attribute__((ext_vector_type(4)));
typedef _Float16 half8 __attribute__((ext_vector_type(8)));
typedef __fp16   fp16x2 __attribute__((ext_vector_type(2)));
typedef uint32_t u32x4 __attribute__((ext_vector_type(4)));

#define SEL_LO 0x05040100u   // v_perm: lo fp16 halves (tile A rows 0..15)
#define SEL_HI 0x07060302u   // hi fp16 halves (tile B rows 16..31)

static __device__ __forceinline__ float fast_tanh(float x) {
    // tanh(x) = 1 - 2/(exp(2x)+1)
    float e = __builtin_amdgcn_exp2f(x * 2.8853900817779268f);
    return 1.0f - 2.0f * __builtin_amdgcn_rcpf(e + 1.0f);
}
static __device__ __forceinline__ unsigned pkrtz(float a, float b) {
    fp16x2 h = __builtin_amdgcn_cvt_pkrtz(a, b);    // lo=a (tile A), hi=b (tile B)
    return __builtin_bit_cast(unsigned, h);
}

// ---- prep: kt[lvl][g][q][n][e] = (fp16) K_lvl[g][ q*8+e ][ n ]  (identity k-order)
//      apre[lvl][g][f] = (col<<6) ^ (((col>>1)&3)<<4)   (row-pair layout byte base)
extern "C" __global__ void kprep_kernel(const float* __restrict__ k1, const float* __restrict__ k2,
                                        const float* __restrict__ k3, const float* __restrict__ k4,
                                        const int* __restrict__ i1, const int* __restrict__ i2,
                                        const int* __restrict__ i3, const int* __restrict__ i4,
                                        uint32_t* __restrict__ kt, int* __restrict__ apre) {
    const int bx  = blockIdx.x;                       // 16 blocks x 256
    const int lvl = bx >> 2;
    const float* Kp = (lvl == 0) ? k1 : (lvl == 1) ? k2 : (lvl == 2) ? k3 : k4;
    const int*   Ip = (lvl == 0) ? i1 : (lvl == 1) ? i2 : (lvl == 2) ? i3 : i4;
    const int sub = (bx & 3) * 256 + threadIdx.x;     // 0..1023 = g*64 + q*16 + n
    const int g = sub >> 6, q = (sub >> 4) & 3, n = sub & 15;
    const float* src = Kp + (size_t)(g * 32 + q * 8) * 16 + n;
    const float v0 = src[0],  v1 = src[16], v2 = src[32], v3 = src[48];
    const float v4 = src[64], v5 = src[80], v6 = src[96], v7 = src[112];
    u32x4 pk;
    pk.x = pkrtz(v0, v1); pk.y = pkrtz(v2, v3);
    pk.z = pkrtz(v4, v5); pk.w = pkrtz(v6, v7);
    *(u32x4*)(kt + (size_t)(lvl * 1024 + sub) * 4) = pk;

    if ((bx & 3) < 2) {                               // 512 idx entries per level
        const int f = (bx & 3) * 256 + threadIdx.x;
        const int col = Ip[f];
        apre[lvl * 512 + f] = (col << 6) ^ (((col >> 1) & 3) << 4);
    }
}

// ---- main ----
// ftile: col-major, 16 row-PAIRS per col (pair p = fp16 rows (p, p+16) in one u32):
//   byte(pair p, col) = (col<<6) ^ (((col>>1)&3)<<4) ^ (p<<2)
// Level 1 gathers its A-fragments straight from global x (L3-hot) -> no first barrier;
// levels 2-4 gather from LDS (one ds_read_b32 = element for BOTH 16-row tiles).

extern "C" __global__ __launch_bounds__(1024, 8)
void denc_kernel(const float* __restrict__ x,
                 const int* __restrict__ i1, const float* __restrict__ b1,
                 const int* __restrict__ a2, const float* __restrict__ b2,
                 const int* __restrict__ a3, const float* __restrict__ b3,
                 const int* __restrict__ a4, const float* __restrict__ b4,
                 const uint32_t* __restrict__ kt,
                 float* __restrict__ out)
{
    __shared__ int4 ftile[4096];                     // 64 KB
    const char* tfc = (const char*)ftile;

    const int tid  = threadIdx.x;
    const int w    = tid >> 6;                       // wave = group 0..15
    const int lane = tid & 63;
    const int q    = lane >> 4;                      // k-block / D row-quad
    const int n    = lane & 15;                      // A row-pair / B,D col
    const int R0   = blockIdx.x * RPB;
    const int Ln   = n << 2;                         // lane part of LDS gather addr

    // ---- level-1 gather addresses (raw cols) + issue global gathers ----
    const int4 ja = *(const int4*)(i1 + w * 32 + q * 8);
    const int4 jb = *(const int4*)(i1 + w * 32 + q * 8 + 4);
    const float* xr0 = x + (size_t)(R0 + n) * 256;   // my tile-A row
    const float* xr1 = xr0 + 16 * 256;               // my tile-B row
    const float g0l = xr0[ja.x], g0h = xr1[ja.x];
    const float g1l = xr0[ja.y], g1h = xr1[ja.y];
    const float g2l = xr0[ja.z], g2h = xr1[ja.z];
    const float g3l = xr0[ja.w], g3h = xr1[ja.w];
    const float g4l = xr0[jb.x], g4h = xr1[jb.x];
    const float g5l = xr0[jb.y], g5h = xr1[jb.y];
    const float g6l = xr0[jb.z], g6h = xr1[jb.z];
    const float g7l = xr0[jb.w], g7h = xr1[jb.w];

    // ---- stage x to LDS (completes under L1 compute; barrier after L1) ----
    {
        const int c = tid & 255;
        const int j = tid >> 8;                      // 0..3 -> pairs 4j..4j+3
        const float* xb = x + (size_t)R0 * 256 + c;
        uint32_t qp[4];
        #pragma unroll
        for (int k = 0; k < 4; ++k) {
            const int p = j * 4 + k;
            qp[k] = pkrtz(xb[(size_t)p * 256], xb[(size_t)(p + 16) * 256]);
        }
        const int s = (c >> 1) & 3;
        ftile[c * 4 + (j ^ s)] = make_int4((int)qp[0], (int)qp[1], (int)qp[2], (int)qp[3]);
    }

    // prefetch level-2 LDS gather addresses
    int4 pa = *(const int4*)(a2 + w * 32 + q * 8);
    int4 pb = *(const int4*)(a2 + w * 32 + q * 8 + 4);

#define COMPUTE(LVLBASE, Bp, OB, LAST) \
    const u32x4 bf = *(const u32x4*)(kt + (size_t)((LVLBASE) + w * 64 + q * 16 + n) * 4); \
    const float bvv = (Bp)[w * 16 + n]; \
    f32x4 accA = {bvv, bvv, bvv, bvv}, accB = accA; \
    u32x4 fA, fB; \
    fA.x = __builtin_amdgcn_perm(r1, r0, SEL_LO); fB.x = __builtin_amdgcn_perm(r1, r0, SEL_HI); \
    fA.y = __builtin_amdgcn_perm(r3, r2, SEL_LO); fB.y = __builtin_amdgcn_perm(r3, r2, SEL_HI); \
    fA.z = __builtin_amdgcn_perm(r5, r4, SEL_LO); fB.z = __builtin_amdgcn_perm(r5, r4, SEL_HI); \
    fA.w = __builtin_amdgcn_perm(r7, r6, SEL_LO); fB.w = __builtin_amdgcn_perm(r7, r6, SEL_HI); \
    accA = __builtin_amdgcn_mfma_f32_16x16x32_f16( \
        __builtin_bit_cast(half8, fA), __builtin_bit_cast(half8, bf), accA, 0, 0, 0); \
    accB = __builtin_amdgcn_mfma_f32_16x16x32_f16( \
        __builtin_bit_cast(half8, fB), __builtin_bit_cast(half8, bf), accB, 0, 0, 0); \
    const float tA0 = fast_tanh(accA[0]), tA1 = fast_tanh(accA[1]); \
    const float tA2 = fast_tanh(accA[2]), tA3 = fast_tanh(accA[3]); \
    const float tB0 = fast_tanh(accB[0]), tB1 = fast_tanh(accB[1]); \
    const float tB2 = fast_tanh(accB[2]), tB3 = fast_tanh(accB[3]); \
    if (LAST) { \
        float* ob = out + (size_t)(R0 + q * 4) * 256 + w * 16 + n; \
        ob[0]    = tA0; ob[256]  = tA1; ob[512]  = tA2; ob[768]  = tA3; \
        ob[4096] = tB0; ob[4352] = tB1; ob[4608] = tB2; ob[4864] = tB3; \
    } else { \
        const int col = (OB) + w * 16 + n; \
        const int s = (col >> 1) & 3; \
        ftile[col * 4 + (q ^ s)] = make_int4( \
            (int)pkrtz(tA0, tB0), (int)pkrtz(tA1, tB1), \
            (int)pkrtz(tA2, tB2), (int)pkrtz(tA3, tB3)); \
    }

    // ---- level 1: fragments from the global gathers (no barrier needed) ----
    {
        const uint32_t r0 = pkrtz(g0l, g0h);
        const uint32_t r1 = pkrtz(g1l, g1h);
        const uint32_t r2 = pkrtz(g2l, g2h);
        const uint32_t r3 = pkrtz(g3l, g3h);
        const uint32_t r4 = pkrtz(g4l, g4h);
        const uint32_t r5 = pkrtz(g5l, g5h);
        const uint32_t r6 = pkrtz(g6l, g6h);
        const uint32_t r7 = pkrtz(g7l, g7h);
        COMPUTE(0, b1, NIN, 0)
    }

#define LEVEL(ApNext, Bp, LVLBASE, OB, LAST) do { \
    __syncthreads(); \
    const uint32_t r0 = *(const uint32_t*)(tfc + (pa.x ^ Ln)); \
    const uint32_t r1 = *(const uint32_t*)(tfc + (pa.y ^ Ln)); \
    const uint32_t r2 = *(const uint32_t*)(tfc + (pa.z ^ Ln)); \
    const uint32_t r3 = *(const uint32_t*)(tfc + (pa.w ^ Ln)); \
    const uint32_t r4 = *(const uint32_t*)(tfc + (pb.x ^ Ln)); \
    const uint32_t r5 = *(const uint32_t*)(tfc + (pb.y ^ Ln)); \
    const uint32_t r6 = *(const uint32_t*)(tfc + (pb.z ^ Ln)); \
    const uint32_t r7 = *(const uint32_t*)(tfc + (pb.w ^ Ln)); \
    if (!(LAST)) {                                   /* prefetch next level */ \
        pa = *(const int4*)((ApNext) + w * 32 + q * 8); \
        pb = *(const int4*)((ApNext) + w * 32 + q * 8 + 4); \
    } \
    COMPUTE(LVLBASE, Bp, OB, LAST) \
} while (0)

    LEVEL(a3, b2, 1024, NIN + 256, 0);
    LEVEL(a4, b3, 2048, NIN + 512, 0);
    LEVEL(a4, b4, 3072, 0,         1);

#undef LEVEL
#undef COMPUTE
}

extern "C" void kernel_launch(void* const* d_in, const int* in_sizes, int n_in,
                              void* d_out, int out_size, void* d_ws, size_t ws_size,
                              hipStream_t stream) {
    const float* x  = (const float*)d_in[0];
    const float* k1 = (const float*)d_in[1];
    const float* b1 = (const float*)d_in[2];
    const int*   i1 = (const int*)  d_in[3];
    const float* k2 = (const float*)d_in[4];
    const float* b2 = (const float*)d_in[5];
    const int*   i2 = (const int*)  d_in[6];
    const float* k3 = (const float*)d_in[7];
    const float* b3 = (const float*)d_in[8];
    const int*   i3 = (const int*)  d_in[9];
    const float* k4 = (const float*)d_in[10];
    const float* b4 = (const float*)d_in[11];
    const int*   i4 = (const int*)  d_in[12];
    float* out = (float*)d_out;
    uint32_t* kt = (uint32_t*)d_ws;                  // 64 KB
    int* apre = (int*)((char*)d_ws + 65536);         // 8 KB

    hipLaunchKernelGGL(kprep_kernel, dim3(16), dim3(256), 0, stream,
                       k1, k2, k3, k4, i1, i2, i3, i4, kt, apre);

    const int batch = in_sizes[0] / NIN;             // 65536
    hipLaunchKernelGGL(denc_kernel, dim3(batch / RPB), dim3(1024), 0, stream,
                       x, i1, b1, apre + 512, b2, apre + 1024, b3, apre + 1536, b4,
                       (const uint32_t*)kt, out);
}

// Round 13
// 49.349 us; speedup vs baseline: 1.8611x; 1.8611x over previous
//
#include <hip/hip_runtime.h>
#include <stdint.h>

#define NIN 256
#define RPB 64              // rows per block: four 16-row MFMA tiles, pair-packed

typedef float    f32x4 __attribute__((ext_vector_type(4)));
typedef _Float16 half8 __attribute__((ext_vector_type(8)));
typedef __fp16   fp16x2 __attribute__((ext_vector_type(2)));
typedef uint32_t u32x4 __attribute__((ext_vector_type(4)));

#define SEL_LO 0x05040100u   // v_perm: lo fp16 halves (rows r)
#define SEL_HI 0x07060302u   // hi fp16 halves (rows r+16)

static __device__ __forceinline__ float fast_tanh(float x) {
    // tanh(x) = 1 - 2/(exp(2x)+1)
    float e = __builtin_amdgcn_exp2f(x * 2.8853900817779268f);
    return 1.0f - 2.0f * __builtin_amdgcn_rcpf(e + 1.0f);
}
static __device__ __forceinline__ unsigned pkrtz(float a, float b) {
    fp16x2 h = __builtin_amdgcn_cvt_pkrtz(a, b);
    return __builtin_bit_cast(unsigned, h);
}

// ---- prep: kt[lvl][g][q][n][e] = (fp16) K_lvl[g][ q*8+e ][ n ]  (identity k-order)
//      apre[lvl][g][f] = (col<<7) ^ (((col>>1)&3)<<5)   (128B-stride pair layout)
extern "C" __global__ void kprep_kernel(const float* __restrict__ k1, const float* __restrict__ k2,
                                        const float* __restrict__ k3, const float* __restrict__ k4,
                                        const int* __restrict__ i1, const int* __restrict__ i2,
                                        const int* __restrict__ i3, const int* __restrict__ i4,
                                        uint32_t* __restrict__ kt, int* __restrict__ apre) {
    const int bx  = blockIdx.x;                       // 16 blocks x 256
    const int lvl = bx >> 2;
    const float* Kp = (lvl == 0) ? k1 : (lvl == 1) ? k2 : (lvl == 2) ? k3 : k4;
    const int*   Ip = (lvl == 0) ? i1 : (lvl == 1) ? i2 : (lvl == 2) ? i3 : i4;
    const int sub = (bx & 3) * 256 + threadIdx.x;     // 0..1023 = g*64 + q*16 + n
    const int g = sub >> 6, q = (sub >> 4) & 3, n = sub & 15;
    const float* src = Kp + (size_t)(g * 32 + q * 8) * 16 + n;
    const float v0 = src[0],  v1 = src[16], v2 = src[32], v3 = src[48];
    const float v4 = src[64], v5 = src[80], v6 = src[96], v7 = src[112];
    u32x4 pk;
    pk.x = pkrtz(v0, v1); pk.y = pkrtz(v2, v3);
    pk.z = pkrtz(v4, v5); pk.w = pkrtz(v6, v7);
    *(u32x4*)(kt + (size_t)(lvl * 1024 + sub) * 4) = pk;

    if ((bx & 3) < 2) {                               // 512 idx entries per level
        const int f = (bx & 3) * 256 + threadIdx.x;
        const int col = Ip[f];
        apre[lvl * 512 + f] = (col << 7) ^ (((col >> 1) & 3) << 5);
    }
}

// ---- main ----
// ftile: col stride 128 B = 32 row-pairs; dword(pair p, tile t, col) at
//   (col<<7) ^ (T(col)<<5) | (p<<3) | (t<<2),  T = (col>>1)&3  (XOR on p's q-bits)
//   pair p of tile t = fp16 rows (64*blk + 32t + p, +16) packed in one u32.
// One ds_read_b64 at (apre ^ (n<<3)) = pair n for BOTH tiles (q-groups cover all
// 32 banks exactly -> conflict-free at the b64 data minimum, no swizzle needed).

extern "C" __global__ __launch_bounds__(1024, 4)
void denc_kernel(const float* __restrict__ x,
                 const int* __restrict__ a1, const float* __restrict__ b1,
                 const int* __restrict__ a2, const float* __restrict__ b2,
                 const int* __restrict__ a3, const float* __restrict__ b3,
                 const int* __restrict__ a4, const float* __restrict__ b4,
                 const uint32_t* __restrict__ kt,
                 float* __restrict__ out)
{
    __shared__ int4 ftile[8192];                     // 128 KB -> 1 block/CU
    const char* tfc = (const char*)ftile;

    const int tid  = threadIdx.x;
    const int w    = tid >> 6;                       // wave = group 0..15
    const int lane = tid & 63;
    const int q    = lane >> 4;                      // k-block / D row-quad
    const int n    = lane & 15;                      // A row-pair / B,D col
    const int R0   = blockIdx.x * RPB;
    const int Ln   = n << 3;                         // lane part of gather addr

    // ---- stage x: thread covers col c=tid&255, pair-quad j=tid>>8, both tiles ----
    {
        const int c = tid & 255;
        const int j = tid >> 8;                      // 0..3 -> pairs 4j..4j+3
        const float* xb = x + (size_t)R0 * 256 + c;
        uint32_t P0[4], P1[4];
        #pragma unroll
        for (int k = 0; k < 4; ++k) {
            const int p = j * 4 + k;
            P0[k] = pkrtz(xb[(size_t)p * 256],        xb[(size_t)(p + 16) * 256]);
            P1[k] = pkrtz(xb[(size_t)(p + 32) * 256], xb[(size_t)(p + 48) * 256]);
        }
        const int T = (c >> 1) & 3;
        char* base = (char*)ftile + ((c << 7) ^ ((j ^ T) << 5));
        *(int4*)(base)      = make_int4((int)P0[0], (int)P1[0], (int)P0[1], (int)P1[1]);
        *(int4*)(base + 16) = make_int4((int)P0[2], (int)P1[2], (int)P0[3], (int)P1[3]);
    }

    // prefetch level-1 gather addresses
    int4 pa = *(const int4*)(a1 + w * 32 + q * 8);
    int4 pb = *(const int4*)(a1 + w * 32 + q * 8 + 4);

#define TANH4(dst0, dst1, dst2, dst3, av) \
    const float dst0 = fast_tanh(av[0]), dst1 = fast_tanh(av[1]); \
    const float dst2 = fast_tanh(av[2]), dst3 = fast_tanh(av[3]);

#define LEVEL(ApNext, Bp, LVLBASE, OB, LAST) do { \
    __syncthreads(); \
    const uint2 d0 = *(const uint2*)(tfc + (pa.x ^ Ln)); \
    const uint2 d1 = *(const uint2*)(tfc + (pa.y ^ Ln)); \
    const uint2 d2 = *(const uint2*)(tfc + (pa.z ^ Ln)); \
    const uint2 d3 = *(const uint2*)(tfc + (pa.w ^ Ln)); \
    const uint2 d4 = *(const uint2*)(tfc + (pb.x ^ Ln)); \
    const uint2 d5 = *(const uint2*)(tfc + (pb.y ^ Ln)); \
    const uint2 d6 = *(const uint2*)(tfc + (pb.z ^ Ln)); \
    const uint2 d7 = *(const uint2*)(tfc + (pb.w ^ Ln)); \
    if (!(LAST)) {                                   /* prefetch next level */ \
        pa = *(const int4*)((ApNext) + w * 32 + q * 8); \
        pb = *(const int4*)((ApNext) + w * 32 + q * 8 + 4); \
    } \
    const u32x4 bf = *(const u32x4*)(kt + (size_t)((LVLBASE) + w * 64 + q * 16 + n) * 4); \
    const float bvv = (Bp)[w * 16 + n]; \
    f32x4 acA0 = {bvv, bvv, bvv, bvv}, acB0 = acA0, acA1 = acA0, acB1 = acA0; \
    u32x4 fA0, fB0, fA1, fB1; \
    fA0.x = __builtin_amdgcn_perm(d1.x, d0.x, SEL_LO); fB0.x = __builtin_amdgcn_perm(d1.x, d0.x, SEL_HI); \
    fA0.y = __builtin_amdgcn_perm(d3.x, d2.x, SEL_LO); fB0.y = __builtin_amdgcn_perm(d3.x, d2.x, SEL_HI); \
    fA0.z = __builtin_amdgcn_perm(d5.x, d4.x, SEL_LO); fB0.z = __builtin_amdgcn_perm(d5.x, d4.x, SEL_HI); \
    fA0.w = __builtin_amdgcn_perm(d7.x, d6.x, SEL_LO); fB0.w = __builtin_amdgcn_perm(d7.x, d6.x, SEL_HI); \
    fA1.x = __builtin_amdgcn_perm(d1.y, d0.y, SEL_LO); fB1.x = __builtin_amdgcn_perm(d1.y, d0.y, SEL_HI); \
    fA1.y = __builtin_amdgcn_perm(d3.y, d2.y, SEL_LO); fB1.y = __builtin_amdgcn_perm(d3.y, d2.y, SEL_HI); \
    fA1.z = __builtin_amdgcn_perm(d5.y, d4.y, SEL_LO); fB1.z = __builtin_amdgcn_perm(d5.y, d4.y, SEL_HI); \
    fA1.w = __builtin_amdgcn_perm(d7.y, d6.y, SEL_LO); fB1.w = __builtin_amdgcn_perm(d7.y, d6.y, SEL_HI); \
    acA0 = __builtin_amdgcn_mfma_f32_16x16x32_f16( \
        __builtin_bit_cast(half8, fA0), __builtin_bit_cast(half8, bf), acA0, 0, 0, 0); \
    acB0 = __builtin_amdgcn_mfma_f32_16x16x32_f16( \
        __builtin_bit_cast(half8, fB0), __builtin_bit_cast(half8, bf), acB0, 0, 0, 0); \
    acA1 = __builtin_amdgcn_mfma_f32_16x16x32_f16( \
        __builtin_bit_cast(half8, fA1), __builtin_bit_cast(half8, bf), acA1, 0, 0, 0); \
    acB1 = __builtin_amdgcn_mfma_f32_16x16x32_f16( \
        __builtin_bit_cast(half8, fB1), __builtin_bit_cast(half8, bf), acB1, 0, 0, 0); \
    TANH4(tA00, tA01, tA02, tA03, acA0) \
    TANH4(tB00, tB01, tB02, tB03, acB0) \
    TANH4(tA10, tA11, tA12, tA13, acA1) \
    TANH4(tB10, tB11, tB12, tB13, acB1) \
    if (LAST) { \
        float* ob = out + (size_t)(R0 + q * 4) * 256 + w * 16 + n; \
        ob[0]     = tA00; ob[256]   = tA01; ob[512]   = tA02; ob[768]   = tA03; \
        ob[4096]  = tB00; ob[4352]  = tB01; ob[4608]  = tB02; ob[4864]  = tB03; \
        ob[8192]  = tA10; ob[8448]  = tA11; ob[8704]  = tA12; ob[8960]  = tA13; \
        ob[12288] = tB10; ob[12544] = tB11; ob[12800] = tB12; ob[13056] = tB13; \
    } else { \
        const int col = (OB) + w * 16 + n; \
        const int T = (col >> 1) & 3; \
        char* base = (char*)ftile + ((col << 7) ^ ((q ^ T) << 5)); \
        *(int4*)(base)      = make_int4((int)pkrtz(tA00, tB00), (int)pkrtz(tA10, tB10), \
                                        (int)pkrtz(tA01, tB01), (int)pkrtz(tA11, tB11)); \
        *(int4*)(base + 16) = make_int4((int)pkrtz(tA02, tB02), (int)pkrtz(tA12, tB12), \
                                        (int)pkrtz(tA03, tB03), (int)pkrtz(tA13, tB13)); \
    } \
} while (0)

    LEVEL(a2, b1,    0, NIN,       0);
    LEVEL(a3, b2, 1024, NIN + 256, 0);
    LEVEL(a4, b3, 2048, NIN + 512, 0);
    LEVEL(a4, b4, 3072, 0,         1);

#undef LEVEL
#undef TANH4
}

extern "C" void kernel_launch(void* const* d_in, const int* in_sizes, int n_in,
                              void* d_out, int out_size, void* d_ws, size_t ws_size,
                              hipStream_t stream) {
    const float* x  = (const float*)d_in[0];
    const float* k1 = (const float*)d_in[1];
    const float* b1 = (const float*)d_in[2];
    const int*   i1 = (const int*)  d_in[3];
    const float* k2 = (const float*)d_in[4];
    const float* b2 = (const float*)d_in[5];
    const int*   i2 = (const int*)  d_in[6];
    const float* k3 = (const float*)d_in[7];
    const float* b3 = (const float*)d_in[8];
    const int*   i3 = (const int*)  d_in[9];
    const float* k4 = (const float*)d_in[10];
    const float* b4 = (const float*)d_in[11];
    const int*   i4 = (const int*)  d_in[12];
    float* out = (float*)d_out;
    uint32_t* kt = (uint32_t*)d_ws;                  // 64 KB
    int* apre = (int*)((char*)d_ws + 65536);         // 8 KB

    hipLaunchKernelGGL(kprep_kernel, dim3(16), dim3(256), 0, stream,
                       k1, k2, k3, k4, i1, i2, i3, i4, kt, apre);

    const int batch = in_sizes[0] / NIN;             // 65536
    hipLaunchKernelGGL(denc_kernel, dim3(batch / RPB), dim3(1024), 0, stream,
                       x, apre, b1, apre + 512, b2, apre + 1024, b3, apre + 1536, b4,
                       (const uint32_t*)kt, out);
}